// Round 11
// baseline (692.648 us; speedup 1.0000x reference)
//
#include <hip/hip_runtime.h>
#include <hip/hip_bf16.h>

#define N_TOK 16384
#define H_DIM 768
#define I_DIM 3072
#define NEXP 8
#define RBLK 1024   // router grid: 16 contiguous tokens per block; rank depends on this

typedef short bf16x8 __attribute__((ext_vector_type(8)));
typedef float f32x4 __attribute__((ext_vector_type(4)));

__device__ __forceinline__ unsigned short f2bf(float f) {
    unsigned int u = __float_as_uint(f);
    u += 0x7fffu + ((u >> 16) & 1u);
    return (unsigned short)(u >> 16);
}

__device__ __forceinline__ float gelu_tanh(float v) {
    float u = 0.7978845608028654f * (v + 0.044715f * v * v * v);
    float t = __expf(2.0f * fminf(u, 15.0f));
    return 0.5f * v * (1.0f + (t - 1.0f) / (t + 1.0f));
}

__device__ __forceinline__ void gll16(const void* g, void* l) {
    __builtin_amdgcn_global_load_lds(
        (const __attribute__((address_space(1))) unsigned int*)g,
        (__attribute__((address_space(3))) unsigned int*)l, 16, 0, 0);
}

// ---------------- Router: contiguous 16-token strip per block ----------------
__global__ __launch_bounds__(256) void moe_router(
    const float* __restrict__ x, const float* __restrict__ gw,
    unsigned short* __restrict__ xbf,
    int* __restrict__ topidx, float* __restrict__ topw,
    float* __restrict__ partials)
{
    __shared__ float gws[NEXP * H_DIM];  // 24 KB
    __shared__ float red[64];
    const int tid = threadIdx.x;
    for (int i = tid * 4; i < NEXP * H_DIM; i += 1024)
        *(float4*)(gws + i) = *(const float4*)(gw + i);
    __syncthreads();

    const int lane = tid & 63;
    const int wid = tid >> 6;
    const int tbase = blockIdx.x * 16 + wid * 4;

    float lcnt[8], lps[8];
#pragma unroll
    for (int e = 0; e < 8; ++e) { lcnt[e] = 0.f; lps[e] = 0.f; }

#pragma unroll
    for (int k = 0; k < 4; ++k) {
        const int t = tbase + k;
        float acc[8] = {0.f, 0.f, 0.f, 0.f, 0.f, 0.f, 0.f, 0.f};
#pragma unroll
        for (int j = 0; j < 3; ++j) {
            const int col = j * 256 + lane * 4;
            float4 xv = *(const float4*)(x + (size_t)t * H_DIM + col);
            ushort4 o;
            o.x = f2bf(xv.x); o.y = f2bf(xv.y); o.z = f2bf(xv.z); o.w = f2bf(xv.w);
            *(ushort4*)(xbf + (size_t)t * H_DIM + col) = o;
#pragma unroll
            for (int e = 0; e < 8; ++e) {
                float4 g = *(const float4*)(gws + e * H_DIM + col);
                acc[e] += xv.x * g.x + xv.y * g.y + xv.z * g.z + xv.w * g.w;
            }
        }
#pragma unroll
        for (int off = 32; off >= 1; off >>= 1)
#pragma unroll
            for (int e = 0; e < 8; ++e) acc[e] += __shfl_xor(acc[e], off, 64);

        int e0 = 0;
#pragma unroll
        for (int e = 1; e < 8; ++e) if (acc[e] > acc[e0]) e0 = e;
        int e1 = (e0 == 0) ? 1 : 0;
#pragma unroll
        for (int e = 0; e < 8; ++e) if (e != e0 && acc[e] > acc[e1]) e1 = e;

        float mx = acc[0];
#pragma unroll
        for (int e = 1; e < 8; ++e) mx = fmaxf(mx, acc[e]);
        float p[8]; float s = 0.f;
#pragma unroll
        for (int e = 0; e < 8; ++e) { p[e] = expf(acc[e] - mx); s += p[e]; }
        float inv = 1.0f / s;
#pragma unroll
        for (int e = 0; e < 8; ++e) p[e] *= inv;

        float wsum = p[e0] + p[e1];
        if (lane == 0) {
            topidx[2 * t] = e0; topidx[2 * t + 1] = e1;
            topw[2 * t] = p[e0] / wsum; topw[2 * t + 1] = p[e1] / wsum;
            lcnt[e0] += 1.f; lcnt[e1] += 1.f;
#pragma unroll
            for (int e = 0; e < 8; ++e) lps[e] += p[e];
        }
    }

    if (lane == 0) {
#pragma unroll
        for (int e = 0; e < 8; ++e) {
            red[wid * 16 + e] = lcnt[e];
            red[wid * 16 + 8 + e] = lps[e];
        }
    }
    __syncthreads();
    if (tid < 16)
        partials[blockIdx.x * 16 + tid] =
            red[tid] + red[16 + tid] + red[32 + tid] + red[48 + tid];
}

// ------- fused rank (+offsets +aux): one block per 16-token strip -------
__global__ __launch_bounds__(256) void moe_rank(
    const int* __restrict__ topidx, const float* __restrict__ topw,
    const float* __restrict__ partials, int* __restrict__ offs,
    float* __restrict__ aux_out, int* __restrict__ perm, float* __restrict__ pw)
{
    const int b = blockIdx.x;
    const int tid = threadIdx.x;
    __shared__ float stot[256], spre[256];
    __shared__ float tot[16];
    __shared__ int pfx[8];

    const int c = tid & 15;
    float vtot = 0.f, vpre = 0.f;
    for (int r = tid >> 4; r < RBLK; r += 16) {
        float v = partials[r * 16 + c];
        vtot += v;
        if (r < b) vpre += v;
    }
    stot[tid] = vtot; spre[tid] = vpre;
    __syncthreads();
    if (tid < 16) {
        float t = 0.f, q = 0.f;
#pragma unroll
        for (int k = 0; k < 16; ++k) { t += stot[k * 16 + tid]; q += spre[k * 16 + tid]; }
        tot[tid] = t;
        if (tid < 8) spre[tid] = q;   // reuse: per-expert prefix for this strip
    }
    __syncthreads();
    if (tid == 0) {
        int run = 0;
        float aux = 0.f;
#pragma unroll
        for (int e = 0; e < 8; ++e) {
            pfx[e] = run + (int)(spre[e] + 0.5f);
            aux += (tot[e] / (float)(N_TOK * 2)) * (tot[8 + e] / (float)N_TOK);
            if (b == 0) offs[e] = run;
            run += (int)(tot[e] + 0.5f);
        }
        if (b == 0) { offs[8] = run; *aux_out = 0.01f * 8.0f * aux; }
    }
    __syncthreads();
    if (tid < 32) {
        const int t = b * 16 + (tid >> 1);
        const int slot = tid & 1;
        const int myexp = topidx[2 * t + slot];
        int rank = 0;
#pragma unroll
        for (int ee = 0; ee < 8; ++ee) {
            unsigned long long m = __ballot(myexp == ee);
            if (myexp == ee)
                rank = pfx[ee] + __popcll(m & ((1ull << tid) - 1ull));
        }
        perm[rank] = t;
        pw[rank] = topw[2 * t + slot];
    }
}

// ---------------- fused fp32 -> bf16 convert of w1 and w2 ----------------
__global__ __launch_bounds__(256) void moe_cvt2(
    const float* __restrict__ a, unsigned short* __restrict__ oa,
    const float* __restrict__ bsrc, unsigned short* __restrict__ ob, int n)
{
    int idx = (blockIdx.x * 256 + threadIdx.x) * 4;
    const int stride = gridDim.x * 1024;
    for (; idx < 2 * n; idx += stride) {
        const float* in = (idx < n) ? a : bsrc;
        unsigned short* out = (idx < n) ? oa : ob;
        const int i = (idx < n) ? idx : idx - n;
        float4 v = *(const float4*)(in + i);
        ushort4 o;
        o.x = f2bf(v.x); o.y = f2bf(v.y); o.z = f2bf(v.z); o.w = f2bf(v.w);
        *(ushort4*)(out + i) = o;
    }
}

// ======== 256x256 / 8-wave / BK=64 / 2-dbuf / 4-phase-per-K-tile GEMM core ========
// LDS dbuf slot: row-major [256][64] shorts (32 KB each for A and B), stored with
// chunk swizzle: slot(row, p) holds orig chunk c = p ^ (row&7)  (16B chunks).
// Stage (full cacheline reads): load q: row = q*64 + (tid>>3), dest = linear
// tid*8 + q*4096; source col chunk c = (tid&7) ^ ((tid>>3)&7)  -> 8 lanes cover a
// contiguous 128B row segment (R7-verified algebra, 0 bank conflicts).
// Frag read: row = tile_row + (lane&15), chunk c = ksub*4 + (lane>>4),
// pos p = c ^ (lane&7)  -> pk(ksub) = ((ksub*4 + (lane>>4)) ^ (lane&7)) * 8.
// Phase p (0..3): read A-frag pair {2p, 2p+1} (4 ds_read_b128; B's 8 reads in
// phase 0 held in regs) -> stage half of tile t+1 (phases 0/1) -> barrier ->
// setprio(1) 16 MFMA setprio(0) -> barrier.  vmcnt(0) once per tile at phase 3
// (its loads were issued 2-3 phases earlier). Reads hit dbuf t&1, writes t&1^1:
// disjoint by construction -> no cross-slot hazard.

#define MFMA_(d_, va_, vb_) d_ = __builtin_amdgcn_mfma_f32_16x16x32_bf16(va_, vb_, d_, 0, 0, 0)

#define STAGE_A4(tt, NT)                                                          \
    if ((tt) < (NT)) { const int sd_ = ((tt) & 1) * 16384;                        \
      gll16(asrc0 + (tt) * 64, As + sd_ +     0 + tid * 8);                       \
      gll16(asrc1 + (tt) * 64, As + sd_ +  4096 + tid * 8);                       \
      gll16(asrc2 + (tt) * 64, As + sd_ +  8192 + tid * 8);                       \
      gll16(asrc3 + (tt) * 64, As + sd_ + 12288 + tid * 8); }

#define STAGE_B4(tt, NT)                                                          \
    if ((tt) < (NT)) { const int sd_ = ((tt) & 1) * 16384;                        \
      gll16(bsrc0 + (tt) * 64, Bs + sd_ +     0 + tid * 8);                       \
      gll16(bsrc1 + (tt) * 64, Bs + sd_ +  4096 + tid * 8);                       \
      gll16(bsrc2 + (tt) * 64, Bs + sd_ +  8192 + tid * 8);                       \
      gll16(bsrc3 + (tt) * 64, Bs + sd_ + 12288 + tid * 8); }

#define GEMM_PHASE(I0, VM_OP, ...)                                                \
  { bf16x8 a00 = *(const bf16x8*)(Acur + (I0) * 1024 + pk0);                      \
    bf16x8 a01 = *(const bf16x8*)(Acur + (I0) * 1024 + pk1);                      \
    bf16x8 a10 = *(const bf16x8*)(Acur + ((I0) + 1) * 1024 + pk0);                \
    bf16x8 a11 = *(const bf16x8*)(Acur + ((I0) + 1) * 1024 + pk1);                \
    __VA_ARGS__;                                                                  \
    VM_OP;                                                                        \
    asm volatile("s_barrier" ::: "memory");                                       \
    __builtin_amdgcn_s_setprio(1);                                                \
    MFMA_(acc[I0][0], a00, b00); MFMA_(acc[I0][0], a01, b01);                     \
    MFMA_(acc[I0][1], a00, b10); MFMA_(acc[I0][1], a01, b11);                     \
    MFMA_(acc[I0][2], a00, b20); MFMA_(acc[I0][2], a01, b21);                     \
    MFMA_(acc[I0][3], a00, b30); MFMA_(acc[I0][3], a01, b31);                     \
    MFMA_(acc[(I0)+1][0], a10, b00); MFMA_(acc[(I0)+1][0], a11, b01);             \
    MFMA_(acc[(I0)+1][1], a10, b10); MFMA_(acc[(I0)+1][1], a11, b11);             \
    MFMA_(acc[(I0)+1][2], a10, b20); MFMA_(acc[(I0)+1][2], a11, b21);             \
    MFMA_(acc[(I0)+1][3], a10, b30); MFMA_(acc[(I0)+1][3], a11, b31);             \
    __builtin_amdgcn_s_setprio(0);                                                \
    asm volatile("s_barrier" ::: "memory"); }

#define GEMM_NOP (void)0
#define GEMM_VMDRAIN asm volatile("s_waitcnt vmcnt(0)" ::: "memory")

#define GEMM_KTILE(t, NT)                                                         \
  { const unsigned short* Acur = As + ((t) & 1) * 16384 + rowA;                   \
    const unsigned short* Bcur = Bs + ((t) & 1) * 16384 + rowB;                   \
    bf16x8 b00 = *(const bf16x8*)(Bcur +    0 + pk0);                             \
    bf16x8 b01 = *(const bf16x8*)(Bcur +    0 + pk1);                             \
    bf16x8 b10 = *(const bf16x8*)(Bcur + 1024 + pk0);                             \
    bf16x8 b11 = *(const bf16x8*)(Bcur + 1024 + pk1);                             \
    bf16x8 b20 = *(const bf16x8*)(Bcur + 2048 + pk0);                             \
    bf16x8 b21 = *(const bf16x8*)(Bcur + 2048 + pk1);                             \
    bf16x8 b30 = *(const bf16x8*)(Bcur + 3072 + pk0);                             \
    bf16x8 b31 = *(const bf16x8*)(Bcur + 3072 + pk1);                             \
    GEMM_PHASE(0, GEMM_NOP, STAGE_A4((t) + 1, NT));                               \
    GEMM_PHASE(2, GEMM_NOP, STAGE_B4((t) + 1, NT));                               \
    GEMM_PHASE(4, GEMM_NOP, GEMM_NOP);                                            \
    GEMM_PHASE(6, GEMM_VMDRAIN, GEMM_NOP);                                        \
  }

#define GEMM_PROLOGUE(NT)                                                         \
    STAGE_A4(0, NT); STAGE_B4(0, NT);                                             \
    asm volatile("s_waitcnt vmcnt(0)" ::: "memory");                              \
    asm volatile("s_barrier" ::: "memory");

// ---------------- GEMM1: h = gelu(gather(x) @ w1[e]^T) -> hbuf [rows][3072] ----
__global__ __launch_bounds__(512) void moe_gemm1(
    const unsigned short* __restrict__ xbf,
    const unsigned short* __restrict__ w1bf,
    const int* __restrict__ perm, const int* __restrict__ offs,
    unsigned short* __restrict__ hbuf, int e0)
{
    const int e = e0 + blockIdx.z;
    const int off = offs[e];
    const int n_e = offs[e + 1] - off;
    const int rt = blockIdx.y;
    if (rt * 256 >= n_e) return;
    const int ct = blockIdx.x;                   // 0..11
    const int coff = off - offs[e0];

    __shared__ __align__(16) unsigned short As[2 * 16384];  // 64 KB
    __shared__ __align__(16) unsigned short Bs[2 * 16384];  // 64 KB

    const int tid = threadIdx.x;
    const int lane = tid & 63;
    const int wid = tid >> 6;
    const int wm = wid >> 2, wn = wid & 3;       // wave tile 128x64

    // staging geometry: row = q*64 + (tid>>3), source chunk c (full-line reads)
    const int srow = tid >> 3;                   // 0..63
    const int csw = (tid & 7) ^ (srow & 7);      // chunk 0..7 -> col = csw*8 shorts

    const unsigned short *asrc0, *asrc1, *asrc2, *asrc3;
    const unsigned short *bsrc0, *bsrc1, *bsrc2, *bsrc3;
    {
        int lr[4];
#pragma unroll
        for (int q = 0; q < 4; ++q) {
            int r = rt * 256 + q * 64 + srow;
            lr[q] = (r >= n_e) ? (n_e - 1) : r;
        }
        asrc0 = xbf + (size_t)perm[off + lr[0]] * H_DIM + csw * 8;
        asrc1 = xbf + (size_t)perm[off + lr[1]] * H_DIM + csw * 8;
        asrc2 = xbf + (size_t)perm[off + lr[2]] * H_DIM + csw * 8;
        asrc3 = xbf + (size_t)perm[off + lr[3]] * H_DIM + csw * 8;
        const size_t wb = (size_t)e * I_DIM + ct * 256;
        bsrc0 = w1bf + (wb + 0 * 64 + srow) * H_DIM + csw * 8;
        bsrc1 = w1bf + (wb + 1 * 64 + srow) * H_DIM + csw * 8;
        bsrc2 = w1bf + (wb + 2 * 64 + srow) * H_DIM + csw * 8;
        bsrc3 = w1bf + (wb + 3 * 64 + srow) * H_DIM + csw * 8;
    }

    const int rowA = (wm * 128 + (lane & 15)) * 64;
    const int rowB = (wn * 64 + (lane & 15)) * 64;
    const int pk0 = (((lane >> 4)    ) ^ (lane & 7)) * 8;
    const int pk1 = (((lane >> 4) + 4) ^ (lane & 7)) * 8;

    f32x4 acc[8][4] = {};

    const int NT = H_DIM / 64;                   // 12
    GEMM_PROLOGUE(NT);
    for (int t = 0; t < NT; ++t) { GEMM_KTILE(t, NT); }

    const int rbase = rt * 256 + wm * 128 + (lane >> 4) * 4;
    const int cbase = ct * 256 + wn * 64 + (lane & 15);
#pragma unroll
    for (int i = 0; i < 8; ++i) {
#pragma unroll
        for (int r = 0; r < 4; ++r) {
            const int lr = rbase + i * 16 + r;
            if (lr < n_e) {
                unsigned short* dst = hbuf + (size_t)(coff + lr) * I_DIM + cbase;
#pragma unroll
                for (int j = 0; j < 4; ++j)
                    dst[j * 16] = f2bf(gelu_tanh(acc[i][j][r]));
            }
        }
    }
}

// ---------------- GEMM2: y += w * (h @ w2[e]^T), full K=3072 ----------------
__global__ __launch_bounds__(512) void moe_gemm2(
    const unsigned short* __restrict__ hbuf,
    const unsigned short* __restrict__ w2bf,
    const int* __restrict__ perm, const float* __restrict__ pw,
    const int* __restrict__ offs, float* __restrict__ y, int e0)
{
    const int e = e0 + blockIdx.z;
    const int off = offs[e];
    const int n_e = offs[e + 1] - off;
    const int rt = blockIdx.y;
    if (rt * 256 >= n_e) return;
    const int ct = blockIdx.x;                   // 0..2
    const int coff = off - offs[e0];

    __shared__ __align__(16) unsigned short As[2 * 16384];
    __shared__ __align__(16) unsigned short Bs[2 * 16384];

    const int tid = threadIdx.x;
    const int lane = tid & 63;
    const int wid = tid >> 6;
    const int wm = wid >> 2, wn = wid & 3;

    const int srow = tid >> 3;
    const int csw = (tid & 7) ^ (srow & 7);

    const unsigned short *asrc0, *asrc1, *asrc2, *asrc3;
    const unsigned short *bsrc0, *bsrc1, *bsrc2, *bsrc3;
    {
        int lr[4];
#pragma unroll
        for (int q = 0; q < 4; ++q) {
            int r = rt * 256 + q * 64 + srow;
            lr[q] = (r >= n_e) ? (n_e - 1) : r;
        }
        asrc0 = hbuf + (size_t)(coff + lr[0]) * I_DIM + csw * 8;
        asrc1 = hbuf + (size_t)(coff + lr[1]) * I_DIM + csw * 8;
        asrc2 = hbuf + (size_t)(coff + lr[2]) * I_DIM + csw * 8;
        asrc3 = hbuf + (size_t)(coff + lr[3]) * I_DIM + csw * 8;
        const size_t wb = (size_t)e * H_DIM + ct * 256;
        bsrc0 = w2bf + (wb + 0 * 64 + srow) * I_DIM + csw * 8;
        bsrc1 = w2bf + (wb + 1 * 64 + srow) * I_DIM + csw * 8;
        bsrc2 = w2bf + (wb + 2 * 64 + srow) * I_DIM + csw * 8;
        bsrc3 = w2bf + (wb + 3 * 64 + srow) * I_DIM + csw * 8;
    }

    const int rowA = (wm * 128 + (lane & 15)) * 64;
    const int rowB = (wn * 64 + (lane & 15)) * 64;
    const int pk0 = (((lane >> 4)    ) ^ (lane & 7)) * 8;
    const int pk1 = (((lane >> 4) + 4) ^ (lane & 7)) * 8;

    f32x4 acc[8][4] = {};

    const int NT = I_DIM / 64;                   // 48
    GEMM_PROLOGUE(NT);
    for (int t = 0; t < NT; ++t) { GEMM_KTILE(t, NT); }

    const int rbase = rt * 256 + wm * 128 + (lane >> 4) * 4;
    const int cbase = ct * 256 + wn * 64 + (lane & 15);
#pragma unroll
    for (int i = 0; i < 8; ++i) {
#pragma unroll
        for (int r = 0; r < 4; ++r) {
            const int lr = rbase + i * 16 + r;
            if (lr < n_e) {
                const int token = perm[off + lr];
                const float w = pw[off + lr];
                float* dst = y + (size_t)token * H_DIM + cbase;
#pragma unroll
                for (int j = 0; j < 4; ++j)
                    atomicAdd(dst + j * 16, w * acc[i][j][r]);
            }
        }
    }
}

extern "C" void kernel_launch(void* const* d_in, const int* in_sizes, int n_in,
                              void* d_out, int out_size, void* d_ws, size_t ws_size,
                              hipStream_t stream) {
    const float* x  = (const float*)d_in[0];
    const float* gw = (const float*)d_in[1];
    const float* w1 = (const float*)d_in[2];
    const float* w2 = (const float*)d_in[3];
    float* y = (float*)d_out;  // [N_TOK*H_DIM] + aux at [N_TOK*H_DIM]

    // ---- workspace layout ----
    char* base = (char*)d_ws;
    size_t o = 0;
    unsigned short* xbf  = (unsigned short*)(base + o); o += (size_t)N_TOK * H_DIM * 2;
    unsigned short* w1bf = (unsigned short*)(base + o); o += (size_t)NEXP * I_DIM * H_DIM * 2;
    unsigned short* w2bf = (unsigned short*)(base + o); o += (size_t)NEXP * H_DIM * I_DIM * 2;
    int*   topidx = (int*)(base + o);   o += (size_t)N_TOK * 2 * 4;
    float* topw   = (float*)(base + o); o += (size_t)N_TOK * 2 * 4;
    int*   perm   = (int*)(base + o);   o += (size_t)N_TOK * 2 * 4;
    float* pw     = (float*)(base + o); o += (size_t)N_TOK * 2 * 4;
    float* partials = (float*)(base + o); o += (size_t)RBLK * 16 * 4;
    int*   offs     = (int*)(base + o);   o += 64;
    unsigned short* hbuf = (unsigned short*)(base + o);
    size_t remain = (ws_size > o) ? (ws_size - o) : 0;

    // expert-chunking: hbuf holds full-K h for a group of experts (rows x 3072 bf16).
    long cap_rows = (long)(remain / (size_t)(I_DIM * 2));
    int nch;
    if (cap_rows >= 32768)      nch = 1;
    else if (cap_rows >= 18022) nch = 2;
    else if (cap_rows >= 9011)  nch = 4;
    else                        nch = 8;
    const int G = NEXP / nch;

    hipMemsetAsync(d_out, 0, (size_t)out_size * 4, stream);

    moe_router<<<RBLK, 256, 0, stream>>>(x, gw, xbf, topidx, topw, partials);
    moe_cvt2<<<4096, 256, 0, stream>>>(w1, w1bf, w2, w2bf, NEXP * I_DIM * H_DIM);
    moe_rank<<<RBLK, 256, 0, stream>>>(topidx, topw, partials, offs,
                                       y + (size_t)N_TOK * H_DIM, perm, pw);

    for (int c = 0; c < nch; ++c) {
        const int e0 = c * G;
        moe_gemm1<<<dim3(12, 32, G), 512, 0, stream>>>(
            xbf, w1bf, perm, offs, hbuf, e0);
        moe_gemm2<<<dim3(3, 32, G), 512, 0, stream>>>(
            hbuf, w2bf, perm, pw, offs, y, e0);
    }
}